// Round 6
// baseline (53.894 us; speedup 1.0000x reference)
//
#include <hip/hip_runtime.h>
#include <hip/hip_bf16.h>

// Problem shapes (fixed by reference):
//   codes: [32, 512, 64, 64] f32   (256 MB)
//   sem:   [32, 8, 256, 256] i32   (nearest-downsample -> sem[b,s,4h,4w])
//   out:   [32, 8*512] f32 (as [bs, s*c, 1, 1]); out[b*4096 + s*512 + c]

#define BS     32
#define CS     512
#define SEG    8
#define HS     64
#define WS     64
#define HW     (HS*WS)          // 4096
#define SEMH   256
#define SEMW   256
#define NCHUNK 64               // kernel A: 64-px chunks per batch
#define CPB    2                // kernel B channels per block

typedef float f32x4 __attribute__((ext_vector_type(4)));

// ---------------------------------------------------------------------------
// Kernel A: packed segment-mask byte per downsampled pixel + per-wave counts.
// grid = BS*NCHUNK = 2048 single-wave blocks. Lane = one pixel (h=chunk, w=l).
// ---------------------------------------------------------------------------
__global__ __launch_bounds__(64) void mask_area_kernel(
    const int* __restrict__ sem,
    unsigned char* __restrict__ mask8,   // [BS][HW]
    int* __restrict__ partial)           // [BS][NCHUNK][SEG]
{
    const int blk   = blockIdx.x;
    const int b     = blk >> 6;
    const int chunk = blk & (NCHUNK - 1);
    const int l     = threadIdx.x;       // 0..63 == w

    const int hw = chunk * 64 + l;       // h = chunk, w = l
    const int* p = sem + (size_t)b * SEG * SEMH * SEMW + (chunk * 4) * SEMW + l * 4;

    unsigned int m = 0;
#pragma unroll
    for (int s = 0; s < SEG; ++s)
        if (__builtin_nontemporal_load(p + s * (SEMH * SEMW)) != 0) m |= (1u << s);
    mask8[b * HW + hw] = (unsigned char)m;

    // one ballot per segment (all lanes participate), lane s writes popcount
    unsigned long long bal[SEG];
#pragma unroll
    for (int s = 0; s < SEG; ++s) bal[s] = __ballot((m >> s) & 1u);

    if (l < SEG) {
        unsigned long long mine = 0;
#pragma unroll
        for (int s = 0; s < SEG; ++s) mine = (l == s) ? bal[s] : mine;
        partial[(b * NCHUNK + chunk) * SEG + l] = __popcll(mine);
    }
}

// ---------------------------------------------------------------------------
// Kernel B: one wave per (b, 2-channel group); 8192 blocks -> 8 waves/SIMD.
// All 16 mask dwords for the block are hoisted into registers at entry, so
// the steady-state loop is a pure NT codes stream + FMA body — the compiler
// can pipeline the float4 loads as deep as the VGPR budget allows.
// ---------------------------------------------------------------------------
__global__ __launch_bounds__(64, 8) void seg_mean_kernel(
    const float* __restrict__ codes,
    const unsigned char* __restrict__ mask8,
    const int* __restrict__ partial,
    float* __restrict__ out)
{
    const int blk = blockIdx.x;
    const int b   = blk >> 8;                 // / (CS/CPB=256)
    const int c0  = (blk & 255) * CPB;
    const int l   = threadIdx.x;              // 0..63

    const float* src = codes + ((size_t)b * CS + c0) * HW;
    const unsigned char* mb = mask8 + b * HW;

    // hoist all masks: lane l owns dword (i*64 + l) of the 4 KB mask plane
    unsigned int mw[16];
#pragma unroll
    for (int i = 0; i < 16; ++i)
        mw[i] = *reinterpret_cast<const unsigned int*>(mb + i * 256 + l * 4);

    float acc[CPB][SEG];
    float gl[CPB];
#pragma unroll
    for (int cc = 0; cc < CPB; ++cc) {
        gl[cc] = 0.0f;
#pragma unroll
        for (int s = 0; s < SEG; ++s) acc[cc][s] = 0.0f;
    }

#pragma unroll
    for (int i = 0; i < 16; ++i) {
        const int hw = i * 256 + l * 4;
        const f32x4 v0 = __builtin_nontemporal_load(
            reinterpret_cast<const f32x4*>(src + hw));
        const f32x4 v1 = __builtin_nontemporal_load(
            reinterpret_cast<const f32x4*>(src + HW + hw));
        const unsigned int m4 = mw[i];

#pragma unroll
        for (int s = 0; s < SEG; ++s) {
            const unsigned int w4 = (m4 >> s) & 0x01010101u;
            const float w0 = (float)( w4        & 0xffu);   // v_cvt_f32_ubyte0
            const float w1 = (float)((w4 >> 8)  & 0xffu);   // v_cvt_f32_ubyte1
            const float w2 = (float)((w4 >> 16) & 0xffu);   // v_cvt_f32_ubyte2
            const float w3 = (float)( w4 >> 24        );    // v_cvt_f32_ubyte3
            float a0 = acc[0][s];
            a0 = fmaf(v0.x, w0, a0);
            a0 = fmaf(v0.y, w1, a0);
            a0 = fmaf(v0.z, w2, a0);
            a0 = fmaf(v0.w, w3, a0);
            acc[0][s] = a0;
            float a1 = acc[1][s];
            a1 = fmaf(v1.x, w0, a1);
            a1 = fmaf(v1.y, w1, a1);
            a1 = fmaf(v1.z, w2, a1);
            a1 = fmaf(v1.w, w3, a1);
            acc[1][s] = a1;
        }
        gl[0] += (v0.x + v0.y) + (v0.z + v0.w);
        gl[1] += (v1.x + v1.y) + (v1.z + v1.w);
    }

    // butterfly reduce across the wave
#pragma unroll
    for (int off = 32; off; off >>= 1) {
#pragma unroll
        for (int cc = 0; cc < CPB; ++cc) {
            gl[cc] += __shfl_xor(gl[cc], off);
#pragma unroll
            for (int s = 0; s < SEG; ++s)
                acc[cc][s] += __shfl_xor(acc[cc][s], off);
        }
    }

    // lane-parallel area reduction: lane handles seg = l&7, chunk-group = l>>3
    const int seg = l & 7;
    const int cg  = l >> 3;
    int ai = 0;
#pragma unroll
    for (int k = 0; k < 8; ++k)
        ai += partial[(b * NCHUNK + cg * 8 + k) * SEG + seg];
    ai += __shfl_xor(ai, 8);
    ai += __shfl_xor(ai, 16);
    ai += __shfl_xor(ai, 32);
    const float a = (float)ai;   // lanes 0..7 hold total area for seg l

    if (l < SEG) {
#pragma unroll
        for (int cc = 0; cc < CPB; ++cc) {
            float segsum = 0.0f;
#pragma unroll
            for (int s = 0; s < SEG; ++s)
                segsum = (l == s) ? acc[cc][s] : segsum;
            out[b * (SEG * CS) + l * CS + (c0 + cc)] =
                (a > 0.0f) ? (segsum / a) : (gl[cc] * (1.0f / (float)HW));
        }
    }
}

// ---------------------------------------------------------------------------
extern "C" void kernel_launch(void* const* d_in, const int* in_sizes, int n_in,
                              void* d_out, int out_size, void* d_ws, size_t ws_size,
                              hipStream_t stream) {
    const float* codes = (const float*)d_in[0];
    const int*   sem   = (const int*)d_in[1];
    float*       out   = (float*)d_out;

    unsigned char* mask8   = (unsigned char*)d_ws;                 // BS*HW bytes
    int*           partial = (int*)((char*)d_ws + BS * HW);        // BS*NCHUNK*SEG ints

    mask_area_kernel<<<BS * NCHUNK, 64, 0, stream>>>(sem, mask8, partial);
    seg_mean_kernel<<<BS * CS / CPB, 64, 0, stream>>>(codes, mask8, partial, out);
}

// Round 7
// 51.923 us; speedup vs baseline: 1.0380x; 1.0380x over previous
//
#include <hip/hip_runtime.h>
#include <hip/hip_bf16.h>

// Problem shapes (fixed by reference):
//   codes: [32, 512, 64, 64] f32   (256 MB)
//   sem:   [32, 8, 256, 256] i32   (nearest-downsample -> sem[b,s,4h,4w])
//   out:   [32, 8*512] f32 (as [bs, s*c, 1, 1]); out[b*4096 + s*512 + c]

#define BS     32
#define CS     512
#define SEG    8
#define HS     64
#define WS     64
#define HW     (HS*WS)          // 4096
#define SEMH   256
#define SEMW   256
#define NCHUNK 64               // kernel A: 64-px chunks per batch
#define CPB    2                // kernel B channels per block
#define PF     2                // kernel B software-pipeline depth

typedef float f32x4 __attribute__((ext_vector_type(4)));

// ---------------------------------------------------------------------------
// Kernel A: packed segment-mask byte per downsampled pixel + per-wave counts.
// grid = BS*NCHUNK = 2048 single-wave blocks. Lane = one pixel (h=chunk, w=l).
// ---------------------------------------------------------------------------
__global__ __launch_bounds__(64) void mask_area_kernel(
    const int* __restrict__ sem,
    unsigned char* __restrict__ mask8,   // [BS][HW]
    int* __restrict__ partial)           // [BS][NCHUNK][SEG]
{
    const int blk   = blockIdx.x;
    const int b     = blk >> 6;
    const int chunk = blk & (NCHUNK - 1);
    const int l     = threadIdx.x;       // 0..63 == w

    const int hw = chunk * 64 + l;       // h = chunk, w = l
    const int* p = sem + (size_t)b * SEG * SEMH * SEMW + (chunk * 4) * SEMW + l * 4;

    unsigned int m = 0;
#pragma unroll
    for (int s = 0; s < SEG; ++s)
        if (__builtin_nontemporal_load(p + s * (SEMH * SEMW)) != 0) m |= (1u << s);
    mask8[b * HW + hw] = (unsigned char)m;

    // one ballot per segment (all lanes participate), lane s writes popcount
    unsigned long long bal[SEG];
#pragma unroll
    for (int s = 0; s < SEG; ++s) bal[s] = __ballot((m >> s) & 1u);

    if (l < SEG) {
        unsigned long long mine = 0;
#pragma unroll
        for (int s = 0; s < SEG; ++s) mine = (l == s) ? bal[s] : mine;
        partial[(b * NCHUNK + chunk) * SEG + l] = __popcll(mine);
    }
}

// ---------------------------------------------------------------------------
// Kernel B: one wave per (b, 2-channel group); 8192 blocks -> 8 waves/SIMD.
// Explicit 2-deep software pipeline: iteration i computes while loads for
// i+1 and i+2 are in flight (>=4 codes float4 loads outstanding per wave).
// Masks decoded per segment via (m4>>s)&0x01010101 + v_cvt_f32_ubyteN.
// ---------------------------------------------------------------------------
__global__ __launch_bounds__(64, 8) void seg_mean_kernel(
    const float* __restrict__ codes,
    const unsigned char* __restrict__ mask8,
    const int* __restrict__ partial,
    float* __restrict__ out)
{
    const int blk = blockIdx.x;
    const int b   = blk >> 8;                 // / (CS/CPB=256)
    const int c0  = (blk & 255) * CPB;
    const int l   = threadIdx.x;              // 0..63

    const float* src = codes + ((size_t)b * CS + c0) * HW;
    const unsigned char* mb = mask8 + b * HW;

    float acc[CPB][SEG];
    float gl[CPB];
#pragma unroll
    for (int cc = 0; cc < CPB; ++cc) {
        gl[cc] = 0.0f;
#pragma unroll
        for (int s = 0; s < SEG; ++s) acc[cc][s] = 0.0f;
    }

    // pipeline buffers, statically indexed under full unroll (SSA-renamed)
    f32x4 bv0[16], bv1[16];
    unsigned int bm[16];

#pragma unroll
    for (int j = 0; j < PF; ++j) {
        const int hw = j * 256 + l * 4;
        bv0[j] = *reinterpret_cast<const f32x4*>(src + hw);
        bv1[j] = *reinterpret_cast<const f32x4*>(src + HW + hw);
        bm[j]  = *reinterpret_cast<const unsigned int*>(mb + hw);
    }

#pragma unroll
    for (int i = 0; i < 16; ++i) {
        if (i + PF < 16) {
            const int hw = (i + PF) * 256 + l * 4;
            bv0[i + PF] = *reinterpret_cast<const f32x4*>(src + hw);
            bv1[i + PF] = *reinterpret_cast<const f32x4*>(src + HW + hw);
            bm[i + PF]  = *reinterpret_cast<const unsigned int*>(mb + hw);
        }

        const f32x4 v0 = bv0[i];
        const f32x4 v1 = bv1[i];
        const unsigned int m4 = bm[i];

#pragma unroll
        for (int s = 0; s < SEG; ++s) {
            const unsigned int w4 = (m4 >> s) & 0x01010101u;
            const float w0 = (float)( w4        & 0xffu);   // v_cvt_f32_ubyte0
            const float w1 = (float)((w4 >> 8)  & 0xffu);   // v_cvt_f32_ubyte1
            const float w2 = (float)((w4 >> 16) & 0xffu);   // v_cvt_f32_ubyte2
            const float w3 = (float)( w4 >> 24        );    // v_cvt_f32_ubyte3
            float a0 = acc[0][s];
            a0 = fmaf(v0.x, w0, a0);
            a0 = fmaf(v0.y, w1, a0);
            a0 = fmaf(v0.z, w2, a0);
            a0 = fmaf(v0.w, w3, a0);
            acc[0][s] = a0;
            float a1 = acc[1][s];
            a1 = fmaf(v1.x, w0, a1);
            a1 = fmaf(v1.y, w1, a1);
            a1 = fmaf(v1.z, w2, a1);
            a1 = fmaf(v1.w, w3, a1);
            acc[1][s] = a1;
        }
        gl[0] += (v0.x + v0.y) + (v0.z + v0.w);
        gl[1] += (v1.x + v1.y) + (v1.z + v1.w);
    }

    // butterfly reduce across the wave
#pragma unroll
    for (int off = 32; off; off >>= 1) {
#pragma unroll
        for (int cc = 0; cc < CPB; ++cc) {
            gl[cc] += __shfl_xor(gl[cc], off);
#pragma unroll
            for (int s = 0; s < SEG; ++s)
                acc[cc][s] += __shfl_xor(acc[cc][s], off);
        }
    }

    // lane-parallel area reduction: lane handles seg = l&7, chunk-group = l>>3
    const int seg = l & 7;
    const int cg  = l >> 3;
    int ai = 0;
#pragma unroll
    for (int k = 0; k < 8; ++k)
        ai += partial[(b * NCHUNK + cg * 8 + k) * SEG + seg];
    ai += __shfl_xor(ai, 8);
    ai += __shfl_xor(ai, 16);
    ai += __shfl_xor(ai, 32);
    const float a = (float)ai;   // lanes 0..7 hold total area for seg l

    if (l < SEG) {
#pragma unroll
        for (int cc = 0; cc < CPB; ++cc) {
            float segsum = 0.0f;
#pragma unroll
            for (int s = 0; s < SEG; ++s)
                segsum = (l == s) ? acc[cc][s] : segsum;
            out[b * (SEG * CS) + l * CS + (c0 + cc)] =
                (a > 0.0f) ? (segsum / a) : (gl[cc] * (1.0f / (float)HW));
        }
    }
}

// ---------------------------------------------------------------------------
extern "C" void kernel_launch(void* const* d_in, const int* in_sizes, int n_in,
                              void* d_out, int out_size, void* d_ws, size_t ws_size,
                              hipStream_t stream) {
    const float* codes = (const float*)d_in[0];
    const int*   sem   = (const int*)d_in[1];
    float*       out   = (float*)d_out;

    unsigned char* mask8   = (unsigned char*)d_ws;                 // BS*HW bytes
    int*           partial = (int*)((char*)d_ws + BS * HW);        // BS*NCHUNK*SEG ints

    mask_area_kernel<<<BS * NCHUNK, 64, 0, stream>>>(sem, mask8, partial);
    seg_mean_kernel<<<BS * CS / CPB, 64, 0, stream>>>(codes, mask8, partial, out);
}